// Round 1
// baseline (60.825 us; speedup 1.0000x reference)
//
#include <hip/hip_runtime.h>

// CooccurrenceMatrix: C[b,r,s] = sum_{i,j} [a[b,r,i]==a[b,s,j] & mr_i>0 & ms_j>0] * K[i,j]
//                              / (valid_r * valid_s + 1e-8)
//
// R5: amortize batch staging across r. R4 staged the full 20 KB batch in
// EVERY (b,r) block (2048 blocks x 640 chunks = 1.31M chunk loads, ~40 MB
// L2 traffic). Now one block owns an r-tile of 4: grid 512 x 512 threads,
// staging done ONCE per block (1.25 chunk-loads/thread vs 10), then four
// independent copies of the verified per-r pipeline run in 128-thread
// groups (rg = t>>7).
//  - Staging: identical coalesced int4/float4 -> byte-packed codes
//    (code 20 = masked) + per-chunk mask partial sums, flat-by-chunk LDS.
//  - Readback: s-row stride-5 (5 coprime 32 -> 2-way = free); r-row is
//    wave-uniform (rg constant per wave) -> pure broadcast.
//  - Phase 1 per group: owners ts<105 (v=ts/5, j0=4*(ts%5)) build
//    h[rg][v][j0..j0+3]; K via global dwordx4 (L1-broadcast); zero LDS
//    reads in the loop, no atomics. h base rg*441 is wave-uniform.
//  - Phase 2: gather h[rg][c*21+j]; 21*c mod 32 distinct for c in [0,20]
//    -> exactly conflict-free.
// LDS: 2.5 KB codes + 2.5 KB msum + 4*1.76 KB h ~= 12 KB; 512 thr ->
// 2 blocks/CU on the 512-block grid = 16 waves/CU (same as R4).

#define BB 16
#define WW 128
#define LL 20
#define PL 21                // h row stride; 21c mod 32 distinct for c=0..20
#define RPB 4                // r-rows per block
#define NTH (WW * RPB)       // 512 threads
#define NCH (WW * LL / 4)    // 640 int4 chunks per batch
#define HSTR (PL * PL)       // 441 floats per h table

__global__ __launch_bounds__(NTH) void coocc_kernel(
    const int*   __restrict__ a,     // [B,W,L] int32
    const float* __restrict__ mask,  // [B,W,L] f32
    const float* __restrict__ kern,  // [L,L]   f32
    float*       __restrict__ out)   // [B,W,W] f32
{
    __shared__ unsigned int code_pack[NCH];   // 2.5 KB: 4 codes/word, flat by chunk
    __shared__ float        msum[NCH];        // 2.5 KB: per-chunk mask partial sums
    __shared__ float        h[RPB * HSTR];    // 4 x 441 f32: values 0..19 + zero row 20

    const int t   = threadIdx.x;
    const int bid = blockIdx.x;        // = b*32 + rtile
    const int b   = bid >> 5;
    const int r0  = (bid & 31) * RPB;

    // ---- coalesced staging of batch b, ONCE per block ----
    const int4*   ap = (const int4*)  (a    + b * (WW * LL));
    const float4* mp = (const float4*)(mask + b * (WW * LL));
    {
        const int4   aa = ap[t];
        const float4 mm = mp[t];
        const unsigned int c0 = (mm.x > 0.f) ? (unsigned)aa.x : LL;
        const unsigned int c1 = (mm.y > 0.f) ? (unsigned)aa.y : LL;
        const unsigned int c2 = (mm.z > 0.f) ? (unsigned)aa.z : LL;
        const unsigned int c3 = (mm.w > 0.f) ? (unsigned)aa.w : LL;
        code_pack[t] = c0 | (c1 << 8) | (c2 << 16) | (c3 << 24);
        msum[t]      = (mm.x + mm.y) + (mm.z + mm.w);
    }
    if (t < NCH - NTH) {               // remaining 128 chunks
        const int    e  = t + NTH;
        const int4   aa = ap[e];
        const float4 mm = mp[e];
        const unsigned int c0 = (mm.x > 0.f) ? (unsigned)aa.x : LL;
        const unsigned int c1 = (mm.y > 0.f) ? (unsigned)aa.y : LL;
        const unsigned int c2 = (mm.z > 0.f) ? (unsigned)aa.z : LL;
        const unsigned int c3 = (mm.w > 0.f) ? (unsigned)aa.w : LL;
        code_pack[e] = c0 | (c1 << 8) | (c2 << 16) | (c3 << 24);
        msum[e]      = (mm.x + mm.y) + (mm.z + mm.w);
    }
    __syncthreads();

    const int rg = t >> 7;             // which r of the tile (wave-uniform)
    const int ts = t & (WW - 1);       // role within 128-thread group
    const int r  = r0 + rg;

    // ---- row readback: own s-row (stride-5, free) + r-row (broadcast) ----
    unsigned int cs[5], cr[5];
    float vs = 0.f, vr = 0.f;
    #pragma unroll
    for (int k = 0; k < 5; ++k) {
        cs[k] = code_pack[ts * 5 + k];
        vs   += msum[ts * 5 + k];
        cr[k] = code_pack[r * 5 + k];
        vr   += msum[r * 5 + k];
    }

    // ---- phase 1: per group, owner ts<105 builds h[rg][v][j0..j0+3] ----
    float* hb = h + rg * HSTR;
    if (ts < 105) {
        const int v  = ts / 5;
        const int j0 = (ts - v * 5) * 4;
        float a0 = 0.f, a1 = 0.f, a2 = 0.f, a3 = 0.f;
        if (v < LL) {
            #pragma unroll
            for (int i = 0; i < LL; ++i) {
                const int    cri = (cr[i >> 2] >> ((i & 3) * 8)) & 0xff;
                const float4 kk  = *(const float4*)(kern + i * LL + j0); // L1-broadcast
                const float  f   = (cri == v) ? 1.f : 0.f;
                a0 += f * kk.x; a1 += f * kk.y; a2 += f * kk.z; a3 += f * kk.w;
            }
        }
        hb[v * PL + j0 + 0] = a0;   // v==20 writes the zero sentinel row
        hb[v * PL + j0 + 1] = a1;
        hb[v * PL + j0 + 2] = a2;
        hb[v * PL + j0 + 3] = a3;
    }
    __syncthreads();

    // ---- phase 2: conflict-free branchless gather ----
    float acc = 0.f;
    #pragma unroll
    for (int j = 0; j < LL; ++j) {
        const int c = (cs[j >> 2] >> ((j & 3) * 8)) & 0xff;
        acc += hb[c * PL + j];
    }
    out[(b * WW + r) * WW + ts] = acc / (vr * vs + 1e-8f);
}

extern "C" void kernel_launch(void* const* d_in, const int* in_sizes, int n_in,
                              void* d_out, int out_size, void* d_ws, size_t ws_size,
                              hipStream_t stream) {
    const int*   a    = (const int*)  d_in[0];  // anonymized_nodes [B,W,L]
    const float* mask = (const float*)d_in[1];  // walk_masks       [B,W,L]
    const float* kern = (const float*)d_in[2];  // kernel           [L,L]
    float*       out  = (float*)d_out;          // [B,W,W]

    coocc_kernel<<<BB * (WW / RPB), NTH, 0, stream>>>(a, mask, kern, out);
}